// Round 7
// baseline (79.870 us; speedup 1.0000x reference)
//
#include <hip/hip_runtime.h>
#include <hip/hip_bf16.h>
#include <math.h>

#define BSZ   4096
#define F     26
#define VOC   100000
#define D     64
#define AD    64
#define ND    13
#define FEA   77
#define NPAIR 325
#define NPAD  336    // 21 M-tiles of 16
#define MT    21
#define ERS   36     // e row stride in u32 (144B, 16B-aligned slices)
#define H1    256
#define H2    128
#define H3    64
#define EPSF  1e-5f
#define MROW  4      // k_mlp rows per block

typedef __attribute__((ext_vector_type(8))) short short8;
typedef __attribute__((ext_vector_type(4))) float f32x4;

union FragU { short8 s; unsigned int u[4]; };

__device__ __forceinline__ unsigned int pk2bf(float a, float b) {
  __hip_bfloat162 h = __float22bfloat162_rn(make_float2(a, b));  // v_cvt_pk_bf16_f32
  return *reinterpret_cast<unsigned int*>(&h);
}
__device__ __forceinline__ unsigned short f2bf(float f) {
  unsigned int u = __float_as_uint(f);
  u += 0x7fffu + ((u >> 16) & 1u);
  return (unsigned short)(u >> 16);
}
__device__ __forceinline__ float bflo(unsigned int u) {
  return __uint_as_float(u << 16);
}
__device__ __forceinline__ float bfhi(unsigned int u) {
  return __uint_as_float(u & 0xffff0000u);
}
// VALU-pipe cross-lane add via DPP
template<int CTRL>
__device__ __forceinline__ float dpp_add(float x) {
  int xi = __builtin_bit_cast(int, x);
  int yi = __builtin_amdgcn_update_dpp(xi, xi, CTRL, 0xf, 0xf, false);
  return x + __builtin_bit_cast(float, yi);
}
// full 16-lane-row sum (all lanes get total): xor1, xor2, ror4, ror8
__device__ __forceinline__ float row16_sum(float x) {
  x = dpp_add<0xB1>(x);
  x = dpp_add<0x4E>(x);
  x = dpp_add<0x124>(x);
  x = dpp_add<0x128>(x);
  return x;
}

// ------- K1: attention. One WAVE per batch row, bf16 e-tile, 1 barrier. ----
__global__ __launch_bounds__(256, 4) void k_attn(
    const int* __restrict__ sx, const float* __restrict__ dx,
    const float* __restrict__ emb, const float* __restrict__ attW,
    const float* __restrict__ attb, const float* __restrict__ attdW,
    const float* __restrict__ attdb, float* __restrict__ x)
{
  __shared__ __align__(16) unsigned int e_all[4][27 * ERS]; // bf16-packed, row 26 = 0
  __shared__ __align__(16) float sc_all[4][NPAD];
  __shared__ unsigned short pt[NPAD];

  const int t    = threadIdx.x;
  const int lane = t & 63;
  const int wv   = t >> 6;
  const int b    = blockIdx.x * 4 + wv;

  // pair table (f1 | f2<<8); pads -> zero-row 26
  for (int p = t; p < NPAD; p += 256) {
    int f1 = 26, f2 = 26;
    if (p < NPAIR) {
      int i = 0, rem = p;
      while (rem >= F - 1 - i) { rem -= F - 1 - i; ++i; }
      f1 = i; f2 = i + 1 + rem;
    }
    pt[p] = (unsigned short)(f1 | (f2 << 8));
  }

  unsigned int* e_w = e_all[wv];
  float* sc_w = sc_all[wv];

  // gather: batched index loads -> batched emb loads -> bf16 LDS stores
  {
    int rowsv[7]; float4 vv[7];
    #pragma unroll
    for (int i = 0; i < 7; ++i) {
      int k = lane + 64 * i, f = k >> 4;
      rowsv[i] = (f < F) ? sx[b * F + f] : 0;
    }
    #pragma unroll
    for (int i = 0; i < 7; ++i) {
      int k = lane + 64 * i, f = k >> 4, q = k & 15;
      float4 v = {0.f, 0.f, 0.f, 0.f};
      if (f < F) v = *(const float4*)&emb[((size_t)f * VOC + rowsv[i]) * D + q * 4];
      vv[i] = v;
    }
    #pragma unroll
    for (int i = 0; i < 7; ++i) {
      int k = lane + 64 * i, f = k >> 4, q = k & 15;
      if (f < 27) {
        uint2 o = { pk2bf(vv[i].x, vv[i].y), pk2bf(vv[i].z, vv[i].w) };
        *(uint2*)&e_w[f * ERS + 2 * q] = o;
      }
    }
  }

  // B fragments (attW columns) + biases — global, L1/L2-resident
  short8 bfrag[2][4];
  float bj[4], dwj[4];
  {
    const int kb = (lane >> 4) * 8;
    const int cl = lane & 15;
    #pragma unroll
    for (int kk = 0; kk < 2; ++kk)
      #pragma unroll
      for (int n = 0; n < 4; ++n)
        #pragma unroll
        for (int j = 0; j < 8; ++j) {
          int k = kk * 32 + kb + j;
          bfrag[kk][n][j] = (short)f2bf(attW[k * AD + n * 16 + cl]);
        }
    #pragma unroll
    for (int n = 0; n < 4; ++n) {
      bj[n]  = attb[n * 16 + cl];
      dwj[n] = attdW[n * 16 + cl];
    }
  }
  const float db0 = attdb[0];

  __syncthreads();   // pt table only (e_w/sc_w are wave-private)

  // ---- phase 1: score GEMM, 21 M-tiles ----
  const int row16 = lane & 15;
  const int kgrp  = lane >> 4;
  const int ku    = kgrp * 4;          // u32 offset of this lane's k-slice
  for (int m = 0; m < MT; ++m) {
    const int prow = m * 16 + row16;
    const unsigned short pp = pt[prow];
    const unsigned int* r1 = &e_w[(pp & 0xff) * ERS];
    const unsigned int* r2 = &e_w[(pp >> 8) * ERS];
    uint4 u1a = *(const uint4*)&r1[ku];
    uint4 u2a = *(const uint4*)&r2[ku];
    uint4 u1b = *(const uint4*)&r1[16 + ku];
    uint4 u2b = *(const uint4*)&r2[16 + ku];
    FragU a0, a1;
    a0.u[0] = pk2bf(bflo(u1a.x)*bflo(u2a.x), bfhi(u1a.x)*bfhi(u2a.x));
    a0.u[1] = pk2bf(bflo(u1a.y)*bflo(u2a.y), bfhi(u1a.y)*bfhi(u2a.y));
    a0.u[2] = pk2bf(bflo(u1a.z)*bflo(u2a.z), bfhi(u1a.z)*bfhi(u2a.z));
    a0.u[3] = pk2bf(bflo(u1a.w)*bflo(u2a.w), bfhi(u1a.w)*bfhi(u2a.w));
    a1.u[0] = pk2bf(bflo(u1b.x)*bflo(u2b.x), bfhi(u1b.x)*bfhi(u2b.x));
    a1.u[1] = pk2bf(bflo(u1b.y)*bflo(u2b.y), bfhi(u1b.y)*bfhi(u2b.y));
    a1.u[2] = pk2bf(bflo(u1b.z)*bflo(u2b.z), bfhi(u1b.z)*bfhi(u2b.z));
    a1.u[3] = pk2bf(bflo(u1b.w)*bflo(u2b.w), bfhi(u1b.w)*bfhi(u2b.w));

    f32x4 acc[4];
    #pragma unroll
    for (int n = 0; n < 4; ++n) {
      f32x4 z = {0.f, 0.f, 0.f, 0.f};
      acc[n] = __builtin_amdgcn_mfma_f32_16x16x32_bf16(a0.s, bfrag[0][n], z, 0, 0, 0);
      acc[n] = __builtin_amdgcn_mfma_f32_16x16x32_bf16(a1.s, bfrag[1][n], acc[n], 0, 0, 0);
    }
    float v4[4];
    #pragma unroll
    for (int r = 0; r < 4; ++r) {
      float val = 0.f;
      #pragma unroll
      for (int n = 0; n < 4; ++n)
        val += fmaxf(acc[n][r] + bj[n], 0.f) * dwj[n];
      v4[r] = row16_sum(val) + db0;   // VALU DPP reduce over 16 lanes
    }
    if (row16 == 0) {
      float4 o = {v4[0], v4[1], v4[2], v4[3]};
      *(float4*)&sc_w[m * 16 + kgrp * 4] = o;
    }
  }

  // ---- phase 2: in-wave softmax over 325 scores ----
  float sv[6], ev[6];
  float mx = -1e30f;
  #pragma unroll
  for (int i = 0; i < 6; ++i) {
    int idx = lane + 64 * i;
    sv[i] = (idx < NPAIR) ? sc_w[idx] : -1e30f;
    mx = fmaxf(mx, sv[i]);
  }
  #pragma unroll
  for (int off = 32; off; off >>= 1) mx = fmaxf(mx, __shfl_xor(mx, off));
  float s = 0.f;
  #pragma unroll
  for (int i = 0; i < 6; ++i) {
    int idx = lane + 64 * i;
    ev[i] = (idx < NPAIR) ? __expf(sv[i] - mx) : 0.f;
    s += ev[i];
  }
  #pragma unroll
  for (int off = 32; off; off >>= 1) s += __shfl_xor(s, off);
  const float invZ = 1.f / s;
  #pragma unroll
  for (int i = 0; i < 6; ++i) {
    int idx = lane + 64 * i;
    if (idx < NPAD) sc_w[idx] = ev[i] * invZ;      // pads get 0
  }

  // ---- phase 3: PV: att_out[d] = sum_p w[p] * e1[d]*e2[d] ----
  const int dblk = lane >> 3;                      // d-block of 8
  const int g    = lane & 7;                       // pair group (consecutive lanes)
  float acc[8] = {0,0,0,0,0,0,0,0};
  for (int it = 0; it < NPAD / 8; ++it) {          // 42 iters
    const int p = g + 8 * it;
    const float wgt = sc_w[p];
    const unsigned short pp = pt[p];
    uint4 w1v = *(const uint4*)&e_w[(pp & 0xff) * ERS + dblk * 4];
    uint4 w2v = *(const uint4*)&e_w[(pp >> 8) * ERS + dblk * 4];
    acc[0] = fmaf(wgt, bflo(w1v.x) * bflo(w2v.x), acc[0]);
    acc[1] = fmaf(wgt, bfhi(w1v.x) * bfhi(w2v.x), acc[1]);
    acc[2] = fmaf(wgt, bflo(w1v.y) * bflo(w2v.y), acc[2]);
    acc[3] = fmaf(wgt, bfhi(w1v.y) * bfhi(w2v.y), acc[3]);
    acc[4] = fmaf(wgt, bflo(w1v.z) * bflo(w2v.z), acc[4]);
    acc[5] = fmaf(wgt, bfhi(w1v.z) * bfhi(w2v.z), acc[5]);
    acc[6] = fmaf(wgt, bflo(w1v.w) * bflo(w2v.w), acc[6]);
    acc[7] = fmaf(wgt, bfhi(w1v.w) * bfhi(w2v.w), acc[7]);
  }
  #pragma unroll
  for (int j = 0; j < 8; ++j) {                    // reduce over g (8 consecutive lanes)
    acc[j] = dpp_add<0xB1>(acc[j]);
    acc[j] = dpp_add<0x4E>(acc[j]);
    acc[j] = dpp_add<0x124>(acc[j]);               // row_ror:4 — valid at g==0
  }
  if (g == 0) {                                    // lanes 0,8,..,56
    float* xo = &x[(size_t)b * FEA + dblk * 8];
    #pragma unroll
    for (int j = 0; j < 8; ++j) xo[j] = acc[j];
  }
  if (lane >= 8 && lane < 8 + ND) {
    x[(size_t)b * FEA + D + (lane - 8)] = dx[b * ND + (lane - 8)];
  }
}

// ---------------- K2: batchnorm stats (block per feature) ----------------
__global__ __launch_bounds__(256) void k_bnstats(
    const float* __restrict__ x, const float* __restrict__ gamma,
    const float* __restrict__ beta, float* __restrict__ scale,
    float* __restrict__ shift)
{
  const int f = blockIdx.x;
  const int t = threadIdx.x;
  const int lane = t & 63;
  const int wv = t >> 6;
  double s = 0.0, s2 = 0.0;
  for (int b = t; b < BSZ; b += 256) {
    float v = x[(size_t)b * FEA + f];
    s += v;
    s2 += (double)v * v;
  }
  #pragma unroll
  for (int off = 32; off; off >>= 1) {
    s += __shfl_xor(s, off);
    s2 += __shfl_xor(s2, off);
  }
  __shared__ double rs[4], rs2[4];
  if (lane == 0) { rs[wv] = s; rs2[wv] = s2; }
  __syncthreads();
  if (t == 0) {
    double S = 0.0, S2 = 0.0;
    #pragma unroll
    for (int i = 0; i < 4; ++i) { S += rs[i]; S2 += rs2[i]; }
    double mu = S / BSZ;
    double var = S2 / BSZ - mu * mu;
    float g = gamma[f];
    float scl = (float)((double)g / sqrt(var + (double)EPSF));
    scale[f] = scl;
    shift[f] = beta[f] - (float)mu * scl;
  }
}

// ---------------- K3: MLP (4 rows per block, 1024 blocks) ----------------
__global__ __launch_bounds__(256) void k_mlp(
    const float* __restrict__ x,
    const float* __restrict__ scale, const float* __restrict__ shift,
    const float* __restrict__ w1, const float* __restrict__ b1,
    const float* __restrict__ w2, const float* __restrict__ b2,
    const float* __restrict__ w3, const float* __restrict__ b3,
    const float* __restrict__ wf, const float* __restrict__ bf,
    float* __restrict__ out)
{
  __shared__ float xn[MROW][80];
  __shared__ float h1s[MROW][H1];
  __shared__ float h2s[MROW][H2];
  __shared__ float h3s[MROW][H3];
  const int t = threadIdx.x;
  const int b0 = blockIdx.x * MROW;

  for (int k = t; k < MROW * FEA; k += 256) {
    int r = k / FEA, f = k % FEA;
    xn[r][f] = x[(size_t)(b0 + r) * FEA + f] * scale[f] + shift[f];
  }
  __syncthreads();

  // layer 1: 77 -> 256, thread = output j, 4 rows
  {
    float acc[MROW];
    const float bb = b1[t];
    #pragma unroll
    for (int r = 0; r < MROW; ++r) acc[r] = bb;
    #pragma unroll 8
    for (int d = 0; d < FEA; ++d) {
      float wv = w1[d * H1 + t];
      #pragma unroll
      for (int r = 0; r < MROW; ++r) acc[r] = fmaf(xn[r][d], wv, acc[r]);
    }
    #pragma unroll
    for (int r = 0; r < MROW; ++r) h1s[r][t] = fmaxf(acc[r], 0.f);
  }
  __syncthreads();

  // layer 2: 256 -> 128, j = t&127, 2 rows per half
  {
    const int j = t & 127;
    const int rb = (t >> 7) * 2;
    float acc[2];
    const float bb = b2[j];
    acc[0] = bb; acc[1] = bb;
    #pragma unroll 8
    for (int k = 0; k < H1; ++k) {
      float wv = w2[k * H2 + j];
      acc[0] = fmaf(h1s[rb + 0][k], wv, acc[0]);
      acc[1] = fmaf(h1s[rb + 1][k], wv, acc[1]);
    }
    h2s[rb + 0][j] = fmaxf(acc[0], 0.f);
    h2s[rb + 1][j] = fmaxf(acc[1], 0.f);
  }
  __syncthreads();

  // layer 3: 128 -> 64, j = t&63, 1 row per quarter
  {
    const int j = t & 63;
    const int r = t >> 6;
    float acc = b3[j];
    #pragma unroll 8
    for (int k = 0; k < H2; ++k)
      acc = fmaf(h2s[r][k], w3[k * H3 + j], acc);
    h3s[r][j] = fmaxf(acc, 0.f);
  }
  __syncthreads();

  // final: 64 -> 1 + sigmoid
  if (t < MROW) {
    float acc = bf[0];
    #pragma unroll 8
    for (int k = 0; k < H3; ++k) acc = fmaf(h3s[t][k], wf[k], acc);
    out[b0 + t] = 1.f / (1.f + __expf(-acc));
  }
}

extern "C" void kernel_launch(void* const* d_in, const int* in_sizes, int n_in,
                              void* d_out, int out_size, void* d_ws, size_t ws_size,
                              hipStream_t stream) {
  const int*   sx    = (const int*)  d_in[0];
  const float* dx    = (const float*)d_in[1];
  const float* emb   = (const float*)d_in[2];
  const float* attW  = (const float*)d_in[3];
  const float* attb  = (const float*)d_in[4];
  const float* attdW = (const float*)d_in[5];
  const float* attdb = (const float*)d_in[6];
  const float* gamma = (const float*)d_in[7];
  const float* beta  = (const float*)d_in[8];
  const float* w1    = (const float*)d_in[9];
  const float* b1    = (const float*)d_in[10];
  const float* w2    = (const float*)d_in[11];
  const float* b2    = (const float*)d_in[12];
  const float* w3    = (const float*)d_in[13];
  const float* b3    = (const float*)d_in[14];
  const float* wf    = (const float*)d_in[15];
  const float* bf    = (const float*)d_in[16];
  float* out = (float*)d_out;

  float* x     = (float*)d_ws;              // B*FEA
  float* scale = x + (size_t)BSZ * FEA;     // FEA
  float* shift = scale + FEA;               // FEA

  k_attn<<<BSZ / 4, 256, 0, stream>>>(sx, dx, emb, attW, attb, attdW, attdb, x);
  k_bnstats<<<FEA, 256, 0, stream>>>(x, gamma, beta, scale, shift);
  k_mlp<<<BSZ / MROW, 256, 0, stream>>>(x, scale, shift, w1, b1, w2, b2, w3, b3,
                                        wf, bf, out);
}

// Round 8
// 68.207 us; speedup vs baseline: 1.1710x; 1.1710x over previous
//
#include <hip/hip_runtime.h>
#include <hip/hip_bf16.h>
#include <math.h>

#define BSZ   4096
#define F     26
#define VOC   100000
#define D     64
#define AD    64
#define ND    13
#define FEA   77
#define NPAIR 325
#define NPAD  336    // 21 M-tiles of 16
#define MT    21
#define EP    68     // e row stride in floats (272B, float4-aligned slices)
#define H1    256
#define H2    128
#define H3    64
#define EPSF  1e-5f
#define MROW  8      // k_mlp rows per block

typedef __attribute__((ext_vector_type(8))) short short8;
typedef __attribute__((ext_vector_type(4))) float f32x4;

union FragU { short8 s; unsigned int u[4]; };

__device__ __forceinline__ unsigned int pk2bf(float a, float b) {
  __hip_bfloat162 h = __float22bfloat162_rn(make_float2(a, b));  // v_cvt_pk_bf16_f32
  return *reinterpret_cast<unsigned int*>(&h);
}
__device__ __forceinline__ unsigned short f2bf(float f) {
  unsigned int u = __float_as_uint(f);
  u += 0x7fffu + ((u >> 16) & 1u);
  return (unsigned short)(u >> 16);
}
// VALU-pipe cross-lane add via DPP
template<int CTRL>
__device__ __forceinline__ float dpp_add(float x) {
  int xi = __builtin_bit_cast(int, x);
  int yi = __builtin_amdgcn_update_dpp(xi, xi, CTRL, 0xf, 0xf, false);
  return x + __builtin_bit_cast(float, yi);
}
// full 16-lane-row sum (all lanes get total): xor1, xor2, ror4, ror8
__device__ __forceinline__ float row16_sum(float x) {
  x = dpp_add<0xB1>(x);
  x = dpp_add<0x4E>(x);
  x = dpp_add<0x124>(x);
  x = dpp_add<0x128>(x);
  return x;
}
// broadcast lane L of v to all lanes (compile-time L under full unroll)
__device__ __forceinline__ float bcast_lane(float v, int l) {
  return __builtin_bit_cast(float,
      __builtin_amdgcn_readlane(__builtin_bit_cast(int, v), l));
}

// ------- K1: attention + BN-stats. One WAVE per batch row, 1 barrier. ------
__global__ __launch_bounds__(256, 4) void k_attn(
    const int* __restrict__ sx, const float* __restrict__ dx,
    const float* __restrict__ emb, const float* __restrict__ attW,
    const float* __restrict__ attb, const float* __restrict__ attdW,
    const float* __restrict__ attdb, float* __restrict__ x,
    float* __restrict__ partS, float* __restrict__ partQ)
{
  __shared__ __align__(16) float e_all[4][27 * EP];   // f32 e, row 26 = zeros
  __shared__ __align__(16) float sc_all[4][NPAD];
  __shared__ float xblk[4][80];
  __shared__ unsigned short pt[NPAD];

  const int t    = threadIdx.x;
  const int lane = t & 63;
  const int wv   = t >> 6;
  const int b    = __builtin_amdgcn_readfirstlane(blockIdx.x * 4 + wv);

  // pair table (f1 | f2<<8) for the score phase; pads -> zero-row 26
  for (int p = t; p < NPAD; p += 256) {
    int f1 = 26, f2 = 26;
    if (p < NPAIR) {
      int i = 0, rem = p;
      while (rem >= F - 1 - i) { rem -= F - 1 - i; ++i; }
      f1 = i; f2 = i + 1 + rem;
    }
    pt[p] = (unsigned short)(f1 | (f2 << 8));
  }

  float* e_w  = e_all[wv];
  float* sc_w = sc_all[wv];

  // gather: lane d holds ef[f] = emb[f, sx[b,f], d]; also mirror into LDS
  float ef[F];
  {
    const int* sxb = sx + b * F;
    int rows[F];
    #pragma unroll
    for (int f = 0; f < F; ++f) rows[f] = sxb[f];   // wave-uniform -> s-loads
    #pragma unroll
    for (int f = 0; f < F; ++f)
      ef[f] = emb[((size_t)f * VOC + rows[f]) * D + lane];  // coalesced 256B
    #pragma unroll
    for (int f = 0; f < F; ++f) e_w[f * EP + lane] = ef[f];
    e_w[26 * EP + lane] = 0.f;                      // zero pad row
  }

  // B fragments (attW columns) + biases — global, L1/L2-resident
  short8 bfrag[2][4];
  float bj[4], dwj[4];
  {
    const int kb = (lane >> 4) * 8;
    const int cl = lane & 15;
    #pragma unroll
    for (int kk = 0; kk < 2; ++kk)
      #pragma unroll
      for (int n = 0; n < 4; ++n)
        #pragma unroll
        for (int j = 0; j < 8; ++j) {
          int k = kk * 32 + kb + j;
          bfrag[kk][n][j] = (short)f2bf(attW[k * AD + n * 16 + cl]);
        }
    #pragma unroll
    for (int n = 0; n < 4; ++n) {
      bj[n]  = attb[n * 16 + cl];
      dwj[n] = attdW[n * 16 + cl];
    }
  }
  const float db0 = attdb[0];

  __syncthreads();   // pt table (e_w/sc_w are wave-private)

  // ---- phase 1: score GEMM, 21 M-tiles ----
  const int row16 = lane & 15;
  const int kgrp  = lane >> 4;
  const int k0    = kgrp * 8;
  for (int m = 0; m < MT; ++m) {
    const int prow = m * 16 + row16;
    const unsigned short pp = pt[prow];
    const float* r1 = &e_w[(pp & 0xff) * EP];
    const float* r2 = &e_w[(pp >> 8) * EP];
    float4 x0 = *(const float4*)&r1[k0];
    float4 x1 = *(const float4*)&r1[k0 + 4];
    float4 y0 = *(const float4*)&r2[k0];
    float4 y1 = *(const float4*)&r2[k0 + 4];
    float4 x2 = *(const float4*)&r1[32 + k0];
    float4 x3 = *(const float4*)&r1[32 + k0 + 4];
    float4 y2 = *(const float4*)&r2[32 + k0];
    float4 y3 = *(const float4*)&r2[32 + k0 + 4];
    FragU a0, a1;
    a0.u[0] = pk2bf(x0.x*y0.x, x0.y*y0.y);
    a0.u[1] = pk2bf(x0.z*y0.z, x0.w*y0.w);
    a0.u[2] = pk2bf(x1.x*y1.x, x1.y*y1.y);
    a0.u[3] = pk2bf(x1.z*y1.z, x1.w*y1.w);
    a1.u[0] = pk2bf(x2.x*y2.x, x2.y*y2.y);
    a1.u[1] = pk2bf(x2.z*y2.z, x2.w*y2.w);
    a1.u[2] = pk2bf(x3.x*y3.x, x3.y*y3.y);
    a1.u[3] = pk2bf(x3.z*y3.z, x3.w*y3.w);

    f32x4 acc[4];
    #pragma unroll
    for (int n = 0; n < 4; ++n) {
      f32x4 z = {0.f, 0.f, 0.f, 0.f};
      acc[n] = __builtin_amdgcn_mfma_f32_16x16x32_bf16(a0.s, bfrag[0][n], z, 0, 0, 0);
      acc[n] = __builtin_amdgcn_mfma_f32_16x16x32_bf16(a1.s, bfrag[1][n], acc[n], 0, 0, 0);
    }
    float v4[4];
    #pragma unroll
    for (int r = 0; r < 4; ++r) {
      float val = 0.f;
      #pragma unroll
      for (int n = 0; n < 4; ++n)
        val += fmaxf(acc[n][r] + bj[n], 0.f) * dwj[n];
      v4[r] = row16_sum(val) + db0;   // VALU DPP reduce over 16 lanes
    }
    if (row16 == 0) {
      float4 o = {v4[0], v4[1], v4[2], v4[3]};
      *(float4*)&sc_w[m * 16 + kgrp * 4] = o;
    }
  }

  // ---- phase 2: in-wave softmax over 325 scores (weights stay in regs) ----
  float sv[6], ev[6];
  float mx = -1e30f;
  #pragma unroll
  for (int i = 0; i < 6; ++i) {
    int idx = lane + 64 * i;
    sv[i] = (idx < NPAIR) ? sc_w[idx] : -1e30f;
    mx = fmaxf(mx, sv[i]);
  }
  #pragma unroll
  for (int off = 32; off; off >>= 1) mx = fmaxf(mx, __shfl_xor(mx, off));
  float s = 0.f;
  #pragma unroll
  for (int i = 0; i < 6; ++i) {
    int idx = lane + 64 * i;
    ev[i] = (idx < NPAIR) ? __expf(sv[i] - mx) : 0.f;
    s += ev[i];
  }
  #pragma unroll
  for (int off = 32; off; off >>= 1) s += __shfl_xor(s, off);
  const float invZ = 1.f / s;

  // ---- phase 3: PV fully in registers. lane d owns att_out[d]. ----
  // 325 pairs unrolled; (f1,f2,p) all compile-time -> static reg indexing.
  float pa0 = 0.f, pa1 = 0.f, pa2 = 0.f, pa3 = 0.f;
  {
    int p = 0;
    #pragma unroll
    for (int f1 = 0; f1 < F - 1; ++f1) {
      #pragma unroll
      for (int f2 = f1 + 1; f2 < F; ++f2) {
        const float w = bcast_lane(ev[p >> 6], p & 63);
        const float prod = ef[f1] * ef[f2];
        if ((p & 3) == 0)      pa0 = fmaf(w, prod, pa0);
        else if ((p & 3) == 1) pa1 = fmaf(w, prod, pa1);
        else if ((p & 3) == 2) pa2 = fmaf(w, prod, pa2);
        else                   pa3 = fmaf(w, prod, pa3);
        ++p;
      }
    }
  }
  const float att = ((pa0 + pa1) + (pa2 + pa3)) * invZ;

  // store x (coalesced) + stage row in LDS for BN stats
  x[(size_t)b * FEA + lane] = att;
  xblk[wv][lane] = att;
  if (lane < ND) {
    float dv = dx[b * ND + lane];
    x[(size_t)b * FEA + D + lane] = dv;
    xblk[wv][D + lane] = dv;
  }
  __syncthreads();

  // ---- BN partial stats: one thread per feature, 4 rows, bucketed atomics --
  if (t < FEA) {
    float x0 = xblk[0][t], x1 = xblk[1][t], x2 = xblk[2][t], x3 = xblk[3][t];
    float sS = (x0 + x1) + (x2 + x3);
    float sQ = (x0 * x0 + x1 * x1) + (x2 * x2 + x3 * x3);
    const int bkt = (blockIdx.x & 7) * 80 + t;
    atomicAdd(&partS[bkt], sS);
    atomicAdd(&partQ[bkt], sQ);
  }
}

// ---------------- K2: MLP (8 rows per block) + BN finalize ----------------
__global__ __launch_bounds__(256) void k_mlp(
    const float* __restrict__ x,
    const float* __restrict__ partS, const float* __restrict__ partQ,
    const float* __restrict__ gamma, const float* __restrict__ beta,
    const float* __restrict__ w1, const float* __restrict__ b1,
    const float* __restrict__ w2, const float* __restrict__ b2,
    const float* __restrict__ w3, const float* __restrict__ b3,
    const float* __restrict__ wf, const float* __restrict__ bf,
    float* __restrict__ out)
{
  __shared__ float scs[80], shs[80];
  __shared__ float xn[MROW][80];
  __shared__ float h1s[MROW][H1];
  __shared__ float h2s[MROW][H2];
  __shared__ float h3s[MROW][H3];
  const int t = threadIdx.x;
  const int b0 = blockIdx.x * MROW;

  if (t < FEA) {
    float S = 0.f, Q = 0.f;
    #pragma unroll
    for (int k = 0; k < 8; ++k) {
      S += partS[k * 80 + t];
      Q += partQ[k * 80 + t];
    }
    float mu  = S * (1.f / BSZ);
    float var = Q * (1.f / BSZ) - mu * mu;
    float scl = gamma[t] * rsqrtf(var + EPSF);
    scs[t] = scl;
    shs[t] = beta[t] - mu * scl;
  }
  __syncthreads();

  for (int k = t; k < MROW * FEA; k += 256) {
    int r = k / FEA, f = k % FEA;
    xn[r][f] = x[(size_t)(b0 + r) * FEA + f] * scs[f] + shs[f];
  }
  __syncthreads();

  // layer 1: 77 -> 256 (thread = output j, 8 rows)
  {
    float acc[MROW];
    const float bb = b1[t];
    #pragma unroll
    for (int r = 0; r < MROW; ++r) acc[r] = bb;
    for (int d = 0; d < FEA; ++d) {
      float wv = w1[d * H1 + t];
      #pragma unroll
      for (int r = 0; r < MROW; ++r) acc[r] = fmaf(xn[r][d], wv, acc[r]);
    }
    #pragma unroll
    for (int r = 0; r < MROW; ++r) h1s[r][t] = fmaxf(acc[r], 0.f);
  }
  __syncthreads();

  // layer 2: 256 -> 128 (j = t&127, 4 rows per half)
  {
    const int j = t & 127;
    const int rb = (t >> 7) * 4;
    float acc[4];
    const float bb = b2[j];
    #pragma unroll
    for (int r = 0; r < 4; ++r) acc[r] = bb;
    for (int k = 0; k < H1; ++k) {
      float wv = w2[k * H2 + j];
      #pragma unroll
      for (int r = 0; r < 4; ++r) acc[r] = fmaf(h1s[rb + r][k], wv, acc[r]);
    }
    #pragma unroll
    for (int r = 0; r < 4; ++r) h2s[rb + r][j] = fmaxf(acc[r], 0.f);
  }
  __syncthreads();

  // layer 3: 128 -> 64 (j = t&63, 2 rows per quarter)
  {
    const int j = t & 63;
    const int rb = (t >> 6) * 2;
    float acc[2];
    const float bb = b3[j];
    acc[0] = bb; acc[1] = bb;
    for (int k = 0; k < H2; ++k) {
      float wv = w3[k * H3 + j];
      acc[0] = fmaf(h2s[rb + 0][k], wv, acc[0]);
      acc[1] = fmaf(h2s[rb + 1][k], wv, acc[1]);
    }
    h3s[rb + 0][j] = fmaxf(acc[0], 0.f);
    h3s[rb + 1][j] = fmaxf(acc[1], 0.f);
  }
  __syncthreads();

  // final: 64 -> 1 + sigmoid
  if (t < MROW) {
    float acc = bf[0];
    for (int k = 0; k < H3; ++k) acc = fmaf(h3s[t][k], wf[k], acc);
    out[b0 + t] = 1.f / (1.f + __expf(-acc));
  }
}

extern "C" void kernel_launch(void* const* d_in, const int* in_sizes, int n_in,
                              void* d_out, int out_size, void* d_ws, size_t ws_size,
                              hipStream_t stream) {
  const int*   sx    = (const int*)  d_in[0];
  const float* dx    = (const float*)d_in[1];
  const float* emb   = (const float*)d_in[2];
  const float* attW  = (const float*)d_in[3];
  const float* attb  = (const float*)d_in[4];
  const float* attdW = (const float*)d_in[5];
  const float* attdb = (const float*)d_in[6];
  const float* gamma = (const float*)d_in[7];
  const float* beta  = (const float*)d_in[8];
  const float* w1    = (const float*)d_in[9];
  const float* b1    = (const float*)d_in[10];
  const float* w2    = (const float*)d_in[11];
  const float* b2    = (const float*)d_in[12];
  const float* w3    = (const float*)d_in[13];
  const float* b3    = (const float*)d_in[14];
  const float* wf    = (const float*)d_in[15];
  const float* bf    = (const float*)d_in[16];
  float* out = (float*)d_out;

  float* x     = (float*)d_ws;                    // B*FEA
  float* partS = x + (size_t)BSZ * FEA;           // 8*80
  float* partQ = partS + 8 * 80;                  // 8*80

  hipMemsetAsync(partS, 0, 2 * 8 * 80 * sizeof(float), stream);
  k_attn<<<BSZ / 4, 256, 0, stream>>>(sx, dx, emb, attW, attb, attdW, attdb,
                                      x, partS, partQ);
  k_mlp<<<BSZ / MROW, 256, 0, stream>>>(x, partS, partQ, gamma, beta,
                                        w1, b1, w2, b2, w3, b3, wf, bf, out);
}

// Round 9
// 65.085 us; speedup vs baseline: 1.2272x; 1.0480x over previous
//
#include <hip/hip_runtime.h>
#include <hip/hip_bf16.h>
#include <math.h>

#define BSZ   4096
#define F     26
#define VOC   100000
#define D     64
#define AD    64
#define ND    13
#define FEA   77
#define NPAIR 325
#define NPAD  336    // 21 M-tiles of 16
#define MT    21
#define EP    68     // e row stride in floats (272B, float4-aligned slices)
#define H1    256
#define H2    128
#define H3    64
#define EPSF  1e-5f
#define MROW  4      // k_mlp rows per block (1024 blocks)

typedef __attribute__((ext_vector_type(8))) short short8;
typedef __attribute__((ext_vector_type(4))) float f32x4;

union FragU { short8 s; unsigned int u[4]; };

__device__ __forceinline__ unsigned int pk2bf(float a, float b) {
  __hip_bfloat162 h = __float22bfloat162_rn(make_float2(a, b));  // v_cvt_pk_bf16_f32
  return *reinterpret_cast<unsigned int*>(&h);
}
__device__ __forceinline__ unsigned short f2bf(float f) {
  unsigned int u = __float_as_uint(f);
  u += 0x7fffu + ((u >> 16) & 1u);
  return (unsigned short)(u >> 16);
}
// VALU-pipe cross-lane add via DPP
template<int CTRL>
__device__ __forceinline__ float dpp_add(float x) {
  int xi = __builtin_bit_cast(int, x);
  int yi = __builtin_amdgcn_update_dpp(xi, xi, CTRL, 0xf, 0xf, false);
  return x + __builtin_bit_cast(float, yi);
}
// full 16-lane-row sum (all lanes get total): xor1, xor2, ror4, ror8
__device__ __forceinline__ float row16_sum(float x) {
  x = dpp_add<0xB1>(x);
  x = dpp_add<0x4E>(x);
  x = dpp_add<0x124>(x);
  x = dpp_add<0x128>(x);
  return x;
}
// broadcast lane L of v to all lanes (compile-time L under full unroll)
__device__ __forceinline__ float bcast_lane(float v, int l) {
  return __builtin_bit_cast(float,
      __builtin_amdgcn_readlane(__builtin_bit_cast(int, v), l));
}

// ------- K1: attention + BN-stats. One WAVE per batch row, 1 barrier. ------
__global__ __launch_bounds__(256, 4) void k_attn(
    const int* __restrict__ sx, const float* __restrict__ dx,
    const float* __restrict__ emb, const float* __restrict__ attW,
    const float* __restrict__ attb, const float* __restrict__ attdW,
    const float* __restrict__ attdb, float* __restrict__ x,
    float* __restrict__ partS, float* __restrict__ partQ)
{
  __shared__ __align__(16) float e_all[4][27 * EP];   // f32 e, row 26 = zeros
  __shared__ __align__(16) float sc_all[4][NPAD];
  __shared__ float xblk[4][80];
  __shared__ unsigned short pt[NPAD];

  const int t    = threadIdx.x;
  const int lane = t & 63;
  const int wv   = t >> 6;
  const int b    = __builtin_amdgcn_readfirstlane(blockIdx.x * 4 + wv);

  // pair table (f1 | f2<<8) for the score phase; pads -> zero-row 26
  for (int p = t; p < NPAD; p += 256) {
    int f1 = 26, f2 = 26;
    if (p < NPAIR) {
      int i = 0, rem = p;
      while (rem >= F - 1 - i) { rem -= F - 1 - i; ++i; }
      f1 = i; f2 = i + 1 + rem;
    }
    pt[p] = (unsigned short)(f1 | (f2 << 8));
  }

  float* e_w  = e_all[wv];
  float* sc_w = sc_all[wv];

  // gather straight to LDS (no long-lived register mirror)
  {
    const int* sxb = sx + b * F;
    int rows[F];
    #pragma unroll
    for (int f = 0; f < F; ++f) rows[f] = sxb[f];   // wave-uniform s-loads
    float vf[F];
    #pragma unroll
    for (int f = 0; f < F; ++f)
      vf[f] = emb[((size_t)f * VOC + rows[f]) * D + lane];  // coalesced 256B
    #pragma unroll
    for (int f = 0; f < F; ++f) e_w[f * EP + lane] = vf[f];
    e_w[26 * EP + lane] = 0.f;                      // zero pad row
  }

  // B fragments (attW columns) + biases — global, L1/L2-resident
  short8 bfrag[2][4];
  float bj[4], dwj[4];
  {
    const int kb = (lane >> 4) * 8;
    const int cl = lane & 15;
    #pragma unroll
    for (int kk = 0; kk < 2; ++kk)
      #pragma unroll
      for (int n = 0; n < 4; ++n)
        #pragma unroll
        for (int j = 0; j < 8; ++j) {
          int k = kk * 32 + kb + j;
          bfrag[kk][n][j] = (short)f2bf(attW[k * AD + n * 16 + cl]);
        }
    #pragma unroll
    for (int n = 0; n < 4; ++n) {
      bj[n]  = attb[n * 16 + cl];
      dwj[n] = attdW[n * 16 + cl];
    }
  }
  const float db0 = attdb[0];

  __syncthreads();   // pt table (e_w/sc_w are wave-private)

  // ---- phase 1: score GEMM, 21 M-tiles ----
  const int row16 = lane & 15;
  const int kgrp  = lane >> 4;
  const int k0    = kgrp * 8;
  for (int m = 0; m < MT; ++m) {
    const int prow = m * 16 + row16;
    const unsigned short pp = pt[prow];
    const float* r1 = &e_w[(pp & 0xff) * EP];
    const float* r2 = &e_w[(pp >> 8) * EP];
    float4 x0 = *(const float4*)&r1[k0];
    float4 x1 = *(const float4*)&r1[k0 + 4];
    float4 y0 = *(const float4*)&r2[k0];
    float4 y1 = *(const float4*)&r2[k0 + 4];
    float4 x2 = *(const float4*)&r1[32 + k0];
    float4 x3 = *(const float4*)&r1[32 + k0 + 4];
    float4 y2 = *(const float4*)&r2[32 + k0];
    float4 y3 = *(const float4*)&r2[32 + k0 + 4];
    FragU a0, a1;
    a0.u[0] = pk2bf(x0.x*y0.x, x0.y*y0.y);
    a0.u[1] = pk2bf(x0.z*y0.z, x0.w*y0.w);
    a0.u[2] = pk2bf(x1.x*y1.x, x1.y*y1.y);
    a0.u[3] = pk2bf(x1.z*y1.z, x1.w*y1.w);
    a1.u[0] = pk2bf(x2.x*y2.x, x2.y*y2.y);
    a1.u[1] = pk2bf(x2.z*y2.z, x2.w*y2.w);
    a1.u[2] = pk2bf(x3.x*y3.x, x3.y*y3.y);
    a1.u[3] = pk2bf(x3.z*y3.z, x3.w*y3.w);

    f32x4 acc[4];
    #pragma unroll
    for (int n = 0; n < 4; ++n) {
      f32x4 z = {0.f, 0.f, 0.f, 0.f};
      acc[n] = __builtin_amdgcn_mfma_f32_16x16x32_bf16(a0.s, bfrag[0][n], z, 0, 0, 0);
      acc[n] = __builtin_amdgcn_mfma_f32_16x16x32_bf16(a1.s, bfrag[1][n], acc[n], 0, 0, 0);
    }
    float v4[4];
    #pragma unroll
    for (int r = 0; r < 4; ++r) {
      float val = 0.f;
      #pragma unroll
      for (int n = 0; n < 4; ++n)
        val += fmaxf(acc[n][r] + bj[n], 0.f) * dwj[n];
      v4[r] = row16_sum(val) + db0;   // VALU DPP reduce over 16 lanes
    }
    if (row16 == 0) {
      float4 o = {v4[0], v4[1], v4[2], v4[3]};
      *(float4*)&sc_w[m * 16 + kgrp * 4] = o;
    }
  }

  // ---- phase 2: in-wave softmax over 325 scores (weights stay in regs) ----
  float sv[6], ev[6];
  float mx = -1e30f;
  #pragma unroll
  for (int i = 0; i < 6; ++i) {
    int idx = lane + 64 * i;
    sv[i] = (idx < NPAIR) ? sc_w[idx] : -1e30f;
    mx = fmaxf(mx, sv[i]);
  }
  #pragma unroll
  for (int off = 32; off; off >>= 1) mx = fmaxf(mx, __shfl_xor(mx, off));
  float s = 0.f;
  #pragma unroll
  for (int i = 0; i < 6; ++i) {
    int idx = lane + 64 * i;
    ev[i] = (idx < NPAIR) ? __expf(sv[i] - mx) : 0.f;
    s += ev[i];
  }
  #pragma unroll
  for (int off = 32; off; off >>= 1) s += __shfl_xor(s, off);
  const float invZ = 1.f / s;

  // ---- phase 3: PV in registers; reload e from LDS (bfrag now dead) ----
  float ef[F];
  #pragma unroll
  for (int f = 0; f < F; ++f) ef[f] = e_w[f * EP + lane];

  float pa0 = 0.f, pa1 = 0.f, pa2 = 0.f, pa3 = 0.f;
  {
    int p = 0;
    #pragma unroll
    for (int f1 = 0; f1 < F - 1; ++f1) {
      #pragma unroll
      for (int f2 = f1 + 1; f2 < F; ++f2) {
        const float w = bcast_lane(ev[p >> 6], p & 63);
        const float prod = ef[f1] * ef[f2];
        if ((p & 3) == 0)      pa0 = fmaf(w, prod, pa0);
        else if ((p & 3) == 1) pa1 = fmaf(w, prod, pa1);
        else if ((p & 3) == 2) pa2 = fmaf(w, prod, pa2);
        else                   pa3 = fmaf(w, prod, pa3);
        ++p;
      }
    }
  }
  const float att = ((pa0 + pa1) + (pa2 + pa3)) * invZ;

  // store x (coalesced) + stage row in LDS for BN stats
  x[(size_t)b * FEA + lane] = att;
  xblk[wv][lane] = att;
  if (lane < ND) {
    float dv = dx[b * ND + lane];
    x[(size_t)b * FEA + D + lane] = dv;
    xblk[wv][D + lane] = dv;
  }
  __syncthreads();

  // ---- BN partial stats: one thread per feature, 4 rows, bucketed atomics --
  if (t < FEA) {
    float x0 = xblk[0][t], x1 = xblk[1][t], x2 = xblk[2][t], x3 = xblk[3][t];
    float sS = (x0 + x1) + (x2 + x3);
    float sQ = (x0 * x0 + x1 * x1) + (x2 * x2 + x3 * x3);
    const int bkt = (blockIdx.x & 7) * 80 + t;
    atomicAdd(&partS[bkt], sS);
    atomicAdd(&partQ[bkt], sQ);
  }
}

// ------- K2: MLP (4 rows/block, 1024 blocks), pipelined loads + BN ---------
__global__ __launch_bounds__(256) void k_mlp(
    const float* __restrict__ x,
    const float* __restrict__ partS, const float* __restrict__ partQ,
    const float* __restrict__ gamma, const float* __restrict__ beta,
    const float* __restrict__ w1, const float* __restrict__ b1,
    const float* __restrict__ w2, const float* __restrict__ b2,
    const float* __restrict__ w3, const float* __restrict__ b3,
    const float* __restrict__ wf, const float* __restrict__ bf,
    float* __restrict__ out)
{
  __shared__ float scs[80], shs[80];
  __shared__ float xn[MROW][80];
  __shared__ float h1s[MROW][H1];
  __shared__ float h2s[MROW][H2];
  __shared__ float h3s[MROW][H3];
  const int t = threadIdx.x;
  const int b0 = blockIdx.x * MROW;

  if (t < FEA) {
    float S = 0.f, Q = 0.f;
    #pragma unroll
    for (int k = 0; k < 8; ++k) {
      S += partS[k * 80 + t];
      Q += partQ[k * 80 + t];
    }
    float mu  = S * (1.f / BSZ);
    float var = Q * (1.f / BSZ) - mu * mu;
    float scl = gamma[t] * rsqrtf(var + EPSF);
    scs[t] = scl;
    shs[t] = beta[t] - mu * scl;
  }
  __syncthreads();

  for (int k = t; k < MROW * FEA; k += 256) {
    int r = k / FEA, f = k % FEA;
    xn[r][f] = x[(size_t)(b0 + r) * FEA + f] * scs[f] + shs[f];
  }
  __syncthreads();

  // layer 1: 77 -> 256 (thread = output j; 11-deep weight-load batches)
  {
    float acc[MROW];
    const float bb = b1[t];
    #pragma unroll
    for (int r = 0; r < MROW; ++r) acc[r] = bb;
    for (int d0 = 0; d0 < FEA; d0 += 11) {
      float wl[11];
      #pragma unroll
      for (int u = 0; u < 11; ++u) wl[u] = w1[(d0 + u) * H1 + t];
      #pragma unroll
      for (int u = 0; u < 11; ++u)
        #pragma unroll
        for (int r = 0; r < MROW; ++r)
          acc[r] = fmaf(xn[r][d0 + u], wl[u], acc[r]);
    }
    #pragma unroll
    for (int r = 0; r < MROW; ++r) h1s[r][t] = fmaxf(acc[r], 0.f);
  }
  __syncthreads();

  // layer 2: 256 -> 128 (j = t&127, 2 rows per half; 16-deep batches)
  {
    const int j = t & 127;
    const int rb = (t >> 7) * 2;
    float acc0 = b2[j], acc1 = acc0;
    for (int c0 = 0; c0 < H1; c0 += 16) {
      float wl[16];
      #pragma unroll
      for (int u = 0; u < 16; ++u) wl[u] = w2[(c0 + u) * H2 + j];
      #pragma unroll
      for (int u = 0; u < 16; ++u) {
        acc0 = fmaf(h1s[rb + 0][c0 + u], wl[u], acc0);
        acc1 = fmaf(h1s[rb + 1][c0 + u], wl[u], acc1);
      }
    }
    h2s[rb + 0][j] = fmaxf(acc0, 0.f);
    h2s[rb + 1][j] = fmaxf(acc1, 0.f);
  }
  __syncthreads();

  // layer 3: 128 -> 64 (j = t&63, 1 row per quarter; 16-deep batches)
  {
    const int j = t & 63;
    const int r = t >> 6;
    float acc = b3[j];
    for (int c0 = 0; c0 < H2; c0 += 16) {
      float wl[16];
      #pragma unroll
      for (int u = 0; u < 16; ++u) wl[u] = w3[(c0 + u) * H3 + j];
      #pragma unroll
      for (int u = 0; u < 16; ++u)
        acc = fmaf(h2s[r][c0 + u], wl[u], acc);
    }
    h3s[r][j] = fmaxf(acc, 0.f);
  }
  __syncthreads();

  // final: 64 -> 1 + sigmoid (32 threads, 8-lane DPP reduce)
  if (t < MROW * 8) {
    const int r = t >> 3;
    const int g = t & 7;
    float acc = 0.f;
    #pragma unroll
    for (int u = 0; u < 8; ++u)
      acc = fmaf(h3s[r][g * 8 + u], wf[g * 8 + u], acc);
    acc = dpp_add<0xB1>(acc);
    acc = dpp_add<0x4E>(acc);
    acc = dpp_add<0x124>(acc);      // valid at g==0
    if (g == 0)
      out[b0 + r] = 1.f / (1.f + __expf(-(acc + bf[0])));
  }
}

extern "C" void kernel_launch(void* const* d_in, const int* in_sizes, int n_in,
                              void* d_out, int out_size, void* d_ws, size_t ws_size,
                              hipStream_t stream) {
  const int*   sx    = (const int*)  d_in[0];
  const float* dx    = (const float*)d_in[1];
  const float* emb   = (const float*)d_in[2];
  const float* attW  = (const float*)d_in[3];
  const float* attb  = (const float*)d_in[4];
  const float* attdW = (const float*)d_in[5];
  const float* attdb = (const float*)d_in[6];
  const float* gamma = (const float*)d_in[7];
  const float* beta  = (const float*)d_in[8];
  const float* w1    = (const float*)d_in[9];
  const float* b1    = (const float*)d_in[10];
  const float* w2    = (const float*)d_in[11];
  const float* b2    = (const float*)d_in[12];
  const float* w3    = (const float*)d_in[13];
  const float* b3    = (const float*)d_in[14];
  const float* wf    = (const float*)d_in[15];
  const float* bf    = (const float*)d_in[16];
  float* out = (float*)d_out;

  float* x     = (float*)d_ws;                    // B*FEA
  float* partS = x + (size_t)BSZ * FEA;           // 8*80
  float* partQ = partS + 8 * 80;                  // 8*80

  hipMemsetAsync(partS, 0, 2 * 8 * 80 * sizeof(float), stream);
  k_attn<<<BSZ / 4, 256, 0, stream>>>(sx, dx, emb, attW, attb, attdW, attdb,
                                      x, partS, partQ);
  k_mlp<<<BSZ / MROW, 256, 0, stream>>>(x, partS, partQ, gamma, beta,
                                        w1, b1, w2, b2, w3, b3, wf, bf, out);
}